// Round 8
// baseline (145.973 us; speedup 1.0000x reference)
//
#include <hip/hip_runtime.h>

#define NB 8
#define NA 32
#define NS 16
#define KE 18750        // floats per emotion row
#define K3 43500        // floats per 3dmm row
#define KH_E 9375       // float2 per emotion row
#define KH_3 21750      // float2 per 3dmm row
#define ND3 58
#define NKL 262144      // 4*8*16*512

#define SE_SLABS 10
#define SD_SLABS 22
#define SLABS 32        // 10 E + 22 D per (b,pos)
#define CHE 938         // float2 per E slab (10*938 = 9380 >= 9375)
#define CHD 989         // float2 per D slab (22*989 = 21758 >= 21750)
#define COST_BLOCKS (NB * 8 * SLABS)   // 2048
#define KL_BLOCKS 64
#define KL_PER_THR (NKL / (KL_BLOCKS * 256))   // 16

#define SW_1 0.0050637127f    // sqrt(1/39000)
#define SW_2 0.0471404521f    // sqrt(10/4500)
#define W_E  (1.0f / 18750.0f)

// ---------------------------------------------------------------------------
// blocks [0, KL_BLOCKS): KL partial sums -> atomic klsum   (launched first)
// blocks [KL_BLOCKS, +COST_BLOCKS): pairwise weighted-SSD slab partials
//   float2 loads, depth-1 register prefetch. E: unweighted, scaled at atomic.
// ---------------------------------------------------------------------------
__global__ __launch_bounds__(256, 3) void fused_kernel(
    const float* __restrict__ ge, const float* __restrict__ g3,
    const float* __restrict__ pe, const float* __restrict__ p3,
    const float* __restrict__ mu, const float* __restrict__ sc,
    float* __restrict__ cost, float* __restrict__ klsum)
{
    const int blk = blockIdx.x;
    const int tid = threadIdx.x;
    __shared__ float red[4][64];

    if (blk < KL_BLOCKS) {
        // ---------------- KL part ----------------
        float ks = 0.f;
        #pragma unroll
        for (int it = 0; it < KL_PER_THR; ++it) {
            const int i = blk * (256 * KL_PER_THR) + it * 256 + tid;
            const float m = mu[i], sg = sc[i];
            ks += 0.5f * (sg * sg + m * m - 1.0f) - logf(sg);
        }
        #pragma unroll
        for (int o = 32; o > 0; o >>= 1) ks += __shfl_xor(ks, o);
        const int lane = tid & 63, w = tid >> 6;
        if (lane == 0) red[0][w] = ks;
        __syncthreads();
        if (tid == 0)
            atomicAdd(klsum, red[0][0] + red[0][1] + red[0][2] + red[0][3]);
        return;
    }

    // ---------------- pairwise cost part ----------------
    const int cblk = blk - KL_BLOCKS;
    const int b    = cblk >> 8;          // 256 blocks per b
    const int rem  = cblk & 255;
    const int pos  = rem >> 5;
    const int slab = rem & 31;
    const int s0   = (pos >> 2) * 8;
    const int a0   = (pos & 3) * 8;

    const bool isE = slab < SE_SLABS;

    float acc[64];
    #pragma unroll
    for (int i = 0; i < 64; ++i) acc[i] = 0.f;

    if (isE) {
        // ---- emotion: float2, unweighted SSD, depth-1 prefetch ----
        const int base = slab * CHE;
        const int kend = min(base + CHE, KH_E);
        const float2* __restrict__ P = (const float2*)(pe + (size_t)(b * NS + s0) * KE);
        const float2* __restrict__ G = (const float2*)(ge + (size_t)(b * NA + a0) * KE);

        int kk = base + tid;             // chunk len > 256, first iter valid
        float2 p[8], g[8];
        #pragma unroll
        for (int i = 0; i < 8; ++i) p[i] = P[i * KH_E + kk];
        #pragma unroll
        for (int j = 0; j < 8; ++j) g[j] = G[j * KH_E + kk];

        #pragma unroll 1
        while (kk < kend) {
            const int knext = kk + 256;
            const int kload = (knext < kend) ? knext : kk;   // tail: re-load cur
            float2 pn[8], gn[8];
            #pragma unroll
            for (int i = 0; i < 8; ++i) pn[i] = P[i * KH_E + kload];
            #pragma unroll
            for (int j = 0; j < 8; ++j) gn[j] = G[j * KH_E + kload];

            #pragma unroll
            for (int i = 0; i < 8; ++i)
                #pragma unroll
                for (int j = 0; j < 8; ++j) {
                    const float d0 = p[i].x - g[j].x;
                    const float d1 = p[i].y - g[j].y;
                    float t = fmaf(d0, d0, acc[i * 8 + j]);
                    acc[i * 8 + j] = fmaf(d1, d1, t);
                }

            #pragma unroll
            for (int i = 0; i < 8; ++i) { p[i] = pn[i]; g[i] = gn[i]; }
            kk = knext;
        }
    } else {
        // ---- 3dmm: float2, per-iter uniform weight (52 even), prefetch ----
        const int base = (slab - SE_SLABS) * CHD;
        const int kend = min(base + CHD, KH_3);
        const float2* __restrict__ P = (const float2*)(p3 + (size_t)(b * NS + s0) * K3);
        const float2* __restrict__ G = (const float2*)(g3 + (size_t)(b * NA + a0) * K3);

        int kk = base + tid;             // chunk len > 256, first iter valid
        int col = (2 * kk) % ND3;        // even; both float2 comps same side
        float2 p[8], g[8];
        #pragma unroll
        for (int i = 0; i < 8; ++i) p[i] = P[i * KH_3 + kk];
        #pragma unroll
        for (int j = 0; j < 8; ++j) g[j] = G[j * KH_3 + kk];

        #pragma unroll 1
        while (kk < kend) {
            const int knext = kk + 256;
            const int kload = (knext < kend) ? knext : kk;
            float2 pn[8], gn[8];
            #pragma unroll
            for (int i = 0; i < 8; ++i) pn[i] = P[i * KH_3 + kload];
            #pragma unroll
            for (int j = 0; j < 8; ++j) gn[j] = G[j * KH_3 + kload];

            const float sw = (col < 52) ? SW_1 : SW_2;
            col += 48; if (col >= ND3) col -= ND3;    // advance by 512 % 58

            float2 ps[8], gs[8];
            #pragma unroll
            for (int i = 0; i < 8; ++i) { ps[i].x = p[i].x * sw; ps[i].y = p[i].y * sw; }
            #pragma unroll
            for (int j = 0; j < 8; ++j) { gs[j].x = g[j].x * sw; gs[j].y = g[j].y * sw; }

            #pragma unroll
            for (int i = 0; i < 8; ++i)
                #pragma unroll
                for (int j = 0; j < 8; ++j) {
                    const float d0 = ps[i].x - gs[j].x;
                    const float d1 = ps[i].y - gs[j].y;
                    float t = fmaf(d0, d0, acc[i * 8 + j]);
                    acc[i * 8 + j] = fmaf(d1, d1, t);
                }

            #pragma unroll
            for (int i = 0; i < 8; ++i) { p[i] = pn[i]; g[i] = gn[i]; }
            kk = knext;
        }
    }

    // ---- cross reduction: value-splitting butterfly (63 shfl+add) ----
    const int lane = tid & 63;
    int n = 64;
    #pragma unroll
    for (int step = 0; step < 6; ++step) {
        const int o = 1 << step;
        const bool hi = (lane & o) != 0;
        const int h = n >> 1;
        #pragma unroll
        for (int m = 0; m < h; ++m) {
            const float send = hi ? acc[m] : acc[m + h];
            const float recv = __shfl_xor(send, o);
            acc[m] = (hi ? acc[m + h] : acc[m]) + recv;
        }
        n = h;
    }

    const int w = tid >> 6;
    red[w][__brev((unsigned)lane) >> 26] = acc[0];
    __syncthreads();
    if (tid < 64) {
        float v = red[0][tid] + red[1][tid] + red[2][tid] + red[3][tid];
        if (isE) v *= W_E;
        const int i = tid >> 3, j = tid & 7;
        atomicAdd(&cost[b * (NS * NA) + (s0 + i) * NA + (a0 + j)], v);
    }
}

// 1 block x 128 threads: thread t = (b,s); min over a, mean, add KL.
__global__ __launch_bounds__(128) void finalize_kernel(
    const float* __restrict__ cost, const float* __restrict__ klsum,
    float* __restrict__ out)
{
    const int t = threadIdx.x;
    const float4* row = (const float4*)(cost + t * NA);
    float mn = 1e30f;
    #pragma unroll
    for (int q = 0; q < 8; ++q) {
        const float4 v = row[q];
        mn = fminf(mn, fminf(fminf(v.x, v.y), fminf(v.z, v.w)));
    }
    #pragma unroll
    for (int o = 32; o > 0; o >>= 1) mn += __shfl_xor(mn, o);
    __shared__ float r2[2];
    if ((t & 63) == 0) r2[t >> 6] = mn;
    __syncthreads();
    if (t == 0) {
        const float rec = (r2[0] + r2[1]) * (1.0f / (NB * NS));
        const float kld = klsum[0] * (1.0f / (float)NKL);
        out[0] = fmaf(0.0002f, kld, rec);
        out[1] = rec;
        out[2] = kld;
    }
}

extern "C" void kernel_launch(void* const* d_in, const int* in_sizes, int n_in,
                              void* d_out, int out_size, void* d_ws, size_t ws_size,
                              hipStream_t stream)
{
    const float* ge = (const float*)d_in[0];
    const float* g3 = (const float*)d_in[1];
    const float* pe = (const float*)d_in[2];
    const float* p3 = (const float*)d_in[3];
    const float* mu = (const float*)d_in[4];
    const float* sc = (const float*)d_in[5];

    float* cost  = (float*)d_ws;            // 4096 floats
    float* klsum = cost + NB * NS * NA;     // 1 float

    hipMemsetAsync(d_ws, 0, (NB * NS * NA + 1) * sizeof(float), stream);

    fused_kernel<<<COST_BLOCKS + KL_BLOCKS, 256, 0, stream>>>(
        ge, g3, pe, p3, mu, sc, cost, klsum);
    finalize_kernel<<<1, 128, 0, stream>>>(cost, klsum, (float*)d_out);
}